// Round 1
// baseline (367.781 us; speedup 1.0000x reference)
//
#include <hip/hip_runtime.h>
#include <hip/hip_bf16.h>

typedef __attribute__((ext_vector_type(8))) short bf16x8;
typedef __attribute__((ext_vector_type(4))) float f32x4;
typedef unsigned short u16;
typedef unsigned int u32;

#define B_ 2
#define S_ 2048
#define E_ 2048
#define H_ 16
#define DK_ 128
#define SCALE_ 0.08838834764831845f  // 1/sqrt(128)

#define MFMA16(a,b,c) __builtin_amdgcn_mfma_f32_16x16x32_bf16((a),(b),(c),0,0,0)
#define GLD16(g, l) __builtin_amdgcn_global_load_lds((const __attribute__((address_space(1))) void*)(g), (__attribute__((address_space(3))) void*)(l), 16, 0, 0)

__device__ __forceinline__ float b2f(short s) {
    u32 u = ((u32)(u16)s) << 16;
    float f; __builtin_memcpy(&f, &u, 4); return f;
}
__device__ __forceinline__ short f2b(float f) {
    __hip_bfloat16 h = __float2bfloat16(f);
    short s; __builtin_memcpy(&s, &h, 2); return s;
}

// ---------------- cast f32 -> bf16 (vectorized x4) ----------------
__global__ void cast_f32_bf16(const float* __restrict__ in, __hip_bfloat16* __restrict__ out, int n4) {
    int i = blockIdx.x * blockDim.x + threadIdx.x;
    if (i >= n4) return;
    float4 v = ((const float4*)in)[i];
    __hip_bfloat16 ob[4] = {__float2bfloat16(v.x), __float2bfloat16(v.y),
                            __float2bfloat16(v.z), __float2bfloat16(v.w)};
    ushort4 u; __builtin_memcpy(&u, ob, 8);
    ((ushort4*)out)[i] = u;
}

// ---------------- RoPE (in-place on q or k, (B,H,S,DK) bf16) ----------------
__global__ void rope_kernel(__hip_bfloat16* __restrict__ q, __hip_bfloat16* __restrict__ k,
                            const float* __restrict__ pe) {
    const long i = ((long)blockIdx.x * blockDim.x + threadIdx.x) * 8;
    __hip_bfloat16* p = (blockIdx.y == 0 ? q : k) + i;
    const int d0 = (int)(i & (DK_ - 1));
    const int s  = (int)((i >> 7) & (S_ - 1));
    const float* pp = pe + (size_t)s * DK_ + d0;
    bf16x8 v = *(const bf16x8*)p;
    __hip_bfloat16 ob[8];
    #pragma unroll
    for (int j = 0; j < 4; ++j) {
        float ang = pp[2*j];            // pe repeated: pe[2j]==pe[2j+1]
        float cs = cosf(ang), sn = sinf(ang);
        float e = b2f(v[2*j]), o = b2f(v[2*j+1]);
        ob[2*j]   = __float2bfloat16(e*cs - o*sn);
        ob[2*j+1] = __float2bfloat16(o*cs + e*sn);
    }
    bf16x8 w; __builtin_memcpy(&w, ob, 16);
    *(bf16x8*)p = w;
}

// ---------------- GEMM: C[m][n] = sum_k A[m][k] * W[n][k]  (both row-major, K-contig) ----
// 128x128 tile, BK=64, 4 waves (2x2), each wave 64x64 (4x4 frags of 16x16x32 MFMA).
// LDS staged via global_load_lds w16 with XOR swizzle (byte ^= (row&7)<<4).
// OUTMODE 0: bf16 -> q/k layout (b,h,s,d)     (M=B*S rows, N=H*DK cols)
// OUTMODE 1: bf16 -> vT layout (b,h,d,s)      (M=H*DK rows, N=B*S cols)
// OUTMODE 2: f32 row-major MxN
template<int OUTMODE>
__global__ __launch_bounds__(256, 2)
void gemm_bt(const __hip_bfloat16* __restrict__ A, const __hip_bfloat16* __restrict__ W,
             void* __restrict__ Cout, int M, int N, int K)
{
    __shared__ __align__(16) __hip_bfloat16 As[128 * 64];
    __shared__ __align__(16) __hip_bfloat16 Bs[128 * 64];
    const int tid = threadIdx.x;
    const int lane = tid & 63, wv = tid >> 6;
    const int wr = wv >> 1, wc = wv & 1;
    const int m0 = blockIdx.x * 128, n0 = blockIdx.y * 128;
    const int g = lane >> 4, c = lane & 15;

    f32x4 acc[4][4];
    #pragma unroll
    for (int i = 0; i < 4; ++i)
        #pragma unroll
        for (int j = 0; j < 4; ++j) acc[i][j] = f32x4{0.f, 0.f, 0.f, 0.f};

    for (int k0 = 0; k0 < K; k0 += 64) {
        __syncthreads();
        #pragma unroll
        for (int it = 0; it < 4; ++it) {
            int o = (it * 256 + tid) * 16;
            int row = o >> 7;                       // 64 bf16 = 128B rows
            int colb = (o ^ ((row & 7) << 4)) & 127;  // pre-swizzled source
            GLD16((const char*)(A + (size_t)(m0 + row) * K + k0) + colb, (char*)As + o);
            GLD16((const char*)(W + (size_t)(n0 + row) * K + k0) + colb, (char*)Bs + o);
        }
        __syncthreads();
        #pragma unroll
        for (int ks = 0; ks < 2; ++ks) {
            bf16x8 af[4], bfm[4];
            #pragma unroll
            for (int i = 0; i < 4; ++i) {
                int arow = wr * 64 + i * 16 + c;
                int ab = arow * 128 + ((ks * 64 + g * 16) ^ ((arow & 7) << 4));
                af[i] = *(const bf16x8*)((const char*)As + ab);
                int brow = wc * 64 + i * 16 + c;
                int bb = brow * 128 + ((ks * 64 + g * 16) ^ ((brow & 7) << 4));
                bfm[i] = *(const bf16x8*)((const char*)Bs + bb);
            }
            #pragma unroll
            for (int i = 0; i < 4; ++i)
                #pragma unroll
                for (int j = 0; j < 4; ++j)
                    acc[i][j] = MFMA16(af[i], bfm[j], acc[i][j]);
        }
    }

    // epilogue: C frag layout col = lane&15, row = 4*(lane>>4)+r
    #pragma unroll
    for (int i = 0; i < 4; ++i) {
        #pragma unroll
        for (int j = 0; j < 4; ++j) {
            #pragma unroll
            for (int r = 0; r < 4; ++r) {
                int m = m0 + wr * 64 + i * 16 + 4 * g + r;
                int n = n0 + wc * 64 + j * 16 + c;
                float v = acc[i][j][r];
                if (OUTMODE == 2) {
                    ((float*)Cout)[(size_t)m * N + n] = v;
                } else if (OUTMODE == 0) {
                    // m=(b,s) n=(h,d) -> ((b*16+h)*2048+s)*128+d
                    size_t a = ((size_t)((m >> 11) * 16 + (n >> 7)) * S_ + (m & (S_ - 1))) * DK_ + (n & (DK_ - 1));
                    ((__hip_bfloat16*)Cout)[a] = __float2bfloat16(v);
                } else {
                    // m=(h,d) n=(b,s) -> ((b*16+h)*128+d)*2048+s
                    size_t a = ((size_t)((n >> 11) * 16 + (m >> 7)) * DK_ + (m & (DK_ - 1))) * S_ + (n & (S_ - 1));
                    ((__hip_bfloat16*)Cout)[a] = __float2bfloat16(v);
                }
            }
        }
    }
}

// ---------------- flash attention (causal), 4 waves x 16 q-rows, KVBLK=64 ----------------
__global__ __launch_bounds__(256, 2)
void attn_kernel(const __hip_bfloat16* __restrict__ Q,   // (B,H,S,DK) roped
                 const __hip_bfloat16* __restrict__ Kt,  // (B,H,S,DK) roped
                 const __hip_bfloat16* __restrict__ VT,  // (B,H,DK,S)
                 __hip_bfloat16* __restrict__ O)         // (B,S,H*DK)
{
    __shared__ __align__(16) __hip_bfloat16 Ks[64 * 128];    // [key][d], swizzled
    __shared__ __align__(16) __hip_bfloat16 Vs[128 * 64];    // [d][key], swizzled
    __shared__ __align__(16) __hip_bfloat16 Ps[4][16 * 72];  // per-wave P, padded rows

    const int tid = threadIdx.x, lane = tid & 63, w = tid >> 6;
    const int g = lane >> 4, c = lane & 15;
    const int bh = blockIdx.y, b = bh >> 4, h = bh & 15;
    const int qbase = blockIdx.x * 64;
    const int qw = qbase + w * 16;
    const size_t base_bh = (size_t)bh * S_ * DK_;
    const __hip_bfloat16* Qp = Q + base_bh;
    const __hip_bfloat16* Kp = Kt + base_bh;
    const __hip_bfloat16* Vp = VT + base_bh;

    // Q fragments: lane holds Q[qw+c][ds*32 + g*8 + j]
    bf16x8 qf[4];
    #pragma unroll
    for (int ds = 0; ds < 4; ++ds)
        qf[ds] = *(const bf16x8*)(Qp + (size_t)(qw + c) * DK_ + ds * 32 + g * 8);

    f32x4 oacc[8];
    #pragma unroll
    for (int fd = 0; fd < 8; ++fd) oacc[fd] = f32x4{0.f, 0.f, 0.f, 0.f};
    float M[4], L[4];
    #pragma unroll
    for (int r = 0; r < 4; ++r) { M[r] = -1e30f; L[r] = 0.f; }

    const int ntiles = blockIdx.x + 1;
    for (int t = 0; t < ntiles; ++t) {
        const int kv0 = t * 64;
        __syncthreads();
        #pragma unroll
        for (int it = 0; it < 4; ++it) {  // K tile: [64][128] rows = 256B
            int o = (it * 256 + tid) * 16;
            int row = o >> 8;
            int cb = (o ^ ((row & 7) << 4)) & 255;
            GLD16((const char*)(Kp + (size_t)(kv0 + row) * DK_) + cb, (char*)Ks + o);
        }
        #pragma unroll
        for (int it = 0; it < 4; ++it) {  // V^T tile: [128][64] rows = 128B
            int o = (it * 256 + tid) * 16;
            int row = o >> 7;
            int cb = (o ^ ((row & 7) << 4)) & 127;
            GLD16((const char*)(Vp + (size_t)row * S_ + kv0) + cb, (char*)Vs + o);
        }
        __syncthreads();

        const bool diag = (kv0 + 63 > qw);  // wave-uniform

        // QK^T: sacc[f]: row=q_local=4g+r, col=key=f*16+c
        f32x4 sacc[4];
        #pragma unroll
        for (int f = 0; f < 4; ++f) sacc[f] = f32x4{0.f, 0.f, 0.f, 0.f};
        #pragma unroll
        for (int f = 0; f < 4; ++f) {
            #pragma unroll
            for (int ds = 0; ds < 4; ++ds) {
                int krow = f * 16 + c;
                int kbyt = krow * 256 + ((ds * 64 + g * 16) ^ ((krow & 7) << 4));
                bf16x8 kf = *(const bf16x8*)((const char*)Ks + kbyt);
                sacc[f] = MFMA16(qf[ds], kf, sacc[f]);
            }
        }

        float p[4][4];
        float mt[4] = {-1e30f, -1e30f, -1e30f, -1e30f};
        #pragma unroll
        for (int f = 0; f < 4; ++f)
            #pragma unroll
            for (int r = 0; r < 4; ++r) {
                float v = sacc[f][r] * SCALE_;
                if (diag && (kv0 + f * 16 + c > qw + 4 * g + r)) v = -1e30f;
                p[f][r] = v;
                mt[r] = fmaxf(mt[r], v);
            }
        #pragma unroll
        for (int r = 0; r < 4; ++r) {  // row-max across the 16-lane group
            float v = mt[r];
            v = fmaxf(v, __shfl_xor(v, 1));
            v = fmaxf(v, __shfl_xor(v, 2));
            v = fmaxf(v, __shfl_xor(v, 4));
            v = fmaxf(v, __shfl_xor(v, 8));
            mt[r] = v;
        }
        float alpha[4];
        #pragma unroll
        for (int r = 0; r < 4; ++r) {
            float mn = fmaxf(M[r], mt[r]);
            alpha[r] = __expf(M[r] - mn);
            M[r] = mn;
        }
        // P = exp(s - M); round to bf16 BEFORE summing so num/denom stay consistent
        float lt[4] = {0.f, 0.f, 0.f, 0.f};
        #pragma unroll
        for (int f = 0; f < 4; ++f)
            #pragma unroll
            for (int r = 0; r < 4; ++r) {
                float e = __expf(p[f][r] - M[r]);
                short eb = f2b(e);
                float er = b2f(eb);
                lt[r] += er;
                Ps[w][(4 * g + r) * 72 + f * 16 + c] = *(__hip_bfloat16*)&eb;
            }
        #pragma unroll
        for (int r = 0; r < 4; ++r) {
            float v = lt[r];
            v += __shfl_xor(v, 1);
            v += __shfl_xor(v, 2);
            v += __shfl_xor(v, 4);
            v += __shfl_xor(v, 8);
            L[r] = L[r] * alpha[r] + v;
        }
        #pragma unroll
        for (int fd = 0; fd < 8; ++fd)
            #pragma unroll
            for (int r = 0; r < 4; ++r) oacc[fd][r] *= alpha[r];

        // PV: A = P (row=q=lane&15, k=key), B = V^T rows (col=d)
        #pragma unroll
        for (int ks = 0; ks < 2; ++ks) {
            bf16x8 pf = *(const bf16x8*)&Ps[w][c * 72 + ks * 32 + g * 8];
            #pragma unroll
            for (int fd = 0; fd < 8; ++fd) {
                int vrow = fd * 16 + c;
                int vb = vrow * 128 + ((ks * 64 + g * 16) ^ ((vrow & 7) << 4));
                bf16x8 vf = *(const bf16x8*)((const char*)Vs + vb);
                oacc[fd] = MFMA16(pf, vf, oacc[fd]);
            }
        }
    }

    // epilogue: O[b][s][h*128+d], d = fd*16+c, s = qw+4g+r
    #pragma unroll
    for (int fd = 0; fd < 8; ++fd) {
        #pragma unroll
        for (int r = 0; r < 4; ++r) {
            int s = qw + 4 * g + r;
            size_t a = ((size_t)(b * S_ + s)) * (H_ * DK_) + h * DK_ + fd * 16 + c;
            O[a] = __float2bfloat16(oacc[fd][r] / L[r]);
        }
    }
}

extern "C" void kernel_launch(void* const* d_in, const int* in_sizes, int n_in,
                              void* d_out, int out_size, void* d_ws, size_t ws_size,
                              hipStream_t stream) {
    const float* x  = (const float*)d_in[0];
    const float* wq = (const float*)d_in[1];
    const float* wk = (const float*)d_in[2];
    const float* wv = (const float*)d_in[3];
    const float* wo = (const float*)d_in[4];
    const float* pe = (const float*)d_in[5];
    float* out = (float*)d_out;

    const size_t XE = (size_t)B_ * S_ * E_;   // 8388608
    const size_t WE = (size_t)E_ * H_ * DK_;  // 4194304
    __hip_bfloat16* xb  = (__hip_bfloat16*)d_ws;
    __hip_bfloat16* wqb = xb + XE;
    __hip_bfloat16* wkb = wqb + WE;
    __hip_bfloat16* wvb = wkb + WE;
    __hip_bfloat16* wob = wvb + WE;
    __hip_bfloat16* qb  = wob + WE;  // (B,H,S,DK)
    __hip_bfloat16* kb  = qb + XE;   // (B,H,S,DK)
    __hip_bfloat16* vT  = kb + XE;   // (B,H,DK,S)
    __hip_bfloat16* at  = vT + XE;   // (B*S, H*DK)

    cast_f32_bf16<<<dim3((int)(XE / 4 / 256)), 256, 0, stream>>>(x,  xb,  (int)(XE / 4));
    cast_f32_bf16<<<dim3((int)(WE / 4 / 256)), 256, 0, stream>>>(wq, wqb, (int)(WE / 4));
    cast_f32_bf16<<<dim3((int)(WE / 4 / 256)), 256, 0, stream>>>(wk, wkb, (int)(WE / 4));
    cast_f32_bf16<<<dim3((int)(WE / 4 / 256)), 256, 0, stream>>>(wv, wvb, (int)(WE / 4));
    cast_f32_bf16<<<dim3((int)(WE / 4 / 256)), 256, 0, stream>>>(wo, wob, (int)(WE / 4));

    // Q = x @ wq^T -> (b,h,s,d);  K likewise;  V^T = wv @ x^T -> (b,h,d,s)
    gemm_bt<0><<<dim3(32, 16), 256, 0, stream>>>(xb, wqb, qb, B_ * S_, H_ * DK_, E_);
    gemm_bt<0><<<dim3(32, 16), 256, 0, stream>>>(xb, wkb, kb, B_ * S_, H_ * DK_, E_);
    gemm_bt<1><<<dim3(16, 32), 256, 0, stream>>>(wvb, xb, vT, H_ * DK_, B_ * S_, E_);

    rope_kernel<<<dim3((int)(XE / 8 / 256), 2), 256, 0, stream>>>(qb, kb, pe);

    attn_kernel<<<dim3(S_ / 64, B_ * H_), 256, 0, stream>>>(qb, kb, vT, at);

    gemm_bt<2><<<dim3(32, 16), 256, 0, stream>>>(at, wob, out, B_ * S_, E_, H_ * DK_);
}

// Round 2
// 299.626 us; speedup vs baseline: 1.2275x; 1.2275x over previous
//
#include <hip/hip_runtime.h>
#include <hip/hip_bf16.h>

typedef __attribute__((ext_vector_type(8))) short bf16x8;
typedef __attribute__((ext_vector_type(4))) float f32x4;
typedef unsigned short u16;
typedef unsigned int u32;

#define B_ 2
#define S_ 2048
#define E_ 2048
#define H_ 16
#define DK_ 128
#define SCALE_ 0.08838834764831845f  // 1/sqrt(128)
#define THR_RAW_ 90.5f               // defer-max threshold: 8 / SCALE_

#define MFMA16(a,b,c) __builtin_amdgcn_mfma_f32_16x16x32_bf16((a),(b),(c),0,0,0)
#define GLD16(g, l) __builtin_amdgcn_global_load_lds((const __attribute__((address_space(1))) void*)(g), (__attribute__((address_space(3))) void*)(l), 16, 0, 0)

__device__ __forceinline__ float b2f(short s) {
    u32 u = ((u32)(u16)s) << 16;
    float f; __builtin_memcpy(&f, &u, 4); return f;
}

// ---------------- cast f32 -> bf16 (vectorized x4) ----------------
__global__ void cast_f32_bf16(const float* __restrict__ in, __hip_bfloat16* __restrict__ out, int n4) {
    int i = blockIdx.x * blockDim.x + threadIdx.x;
    if (i >= n4) return;
    float4 v = ((const float4*)in)[i];
    __hip_bfloat16 ob[4] = {__float2bfloat16(v.x), __float2bfloat16(v.y),
                            __float2bfloat16(v.z), __float2bfloat16(v.w)};
    ushort4 u; __builtin_memcpy(&u, ob, 8);
    ((ushort4*)out)[i] = u;
}

// ---------------- RoPE (in-place on q or k, (B,H,S,DK) bf16) ----------------
__global__ void rope_kernel(__hip_bfloat16* __restrict__ q, __hip_bfloat16* __restrict__ k,
                            const float* __restrict__ pe) {
    const long i = ((long)blockIdx.x * blockDim.x + threadIdx.x) * 8;
    __hip_bfloat16* p = (blockIdx.y == 0 ? q : k) + i;
    const int d0 = (int)(i & (DK_ - 1));
    const int s  = (int)((i >> 7) & (S_ - 1));
    const float* pp = pe + (size_t)s * DK_ + d0;
    bf16x8 v = *(const bf16x8*)p;
    __hip_bfloat16 ob[8];
    #pragma unroll
    for (int j = 0; j < 4; ++j) {
        float ang = pp[2*j];            // pe repeated: pe[2j]==pe[2j+1]
        float cs = cosf(ang), sn = sinf(ang);
        float e = b2f(v[2*j]), o = b2f(v[2*j+1]);
        ob[2*j]   = __float2bfloat16(e*cs - o*sn);
        ob[2*j+1] = __float2bfloat16(o*cs + e*sn);
    }
    bf16x8 w; __builtin_memcpy(&w, ob, 16);
    *(bf16x8*)p = w;
}

// ---------------- GEMM: C[m][n] = sum_k A[m][k] * W[n][k]  (both row-major, K-contig) ----
// 128x128 tile, BK=64, 4 waves (2x2), each wave 64x64 (4x4 frags of 16x16x32 MFMA).
// LDS staged via global_load_lds w16 with XOR swizzle (byte ^= (row&7)<<4).
// OUTMODE 0: bf16 -> q/k layout (b,h,s,d)     (M=B*S rows, N=H*DK cols)
// OUTMODE 1: bf16 -> vT layout (b,h,d,s)      (M=H*DK rows, N=B*S cols)
// OUTMODE 2: f32 row-major MxN
template<int OUTMODE>
__global__ __launch_bounds__(256, 2)
void gemm_bt(const __hip_bfloat16* __restrict__ A, const __hip_bfloat16* __restrict__ W,
             void* __restrict__ Cout, int M, int N, int K)
{
    __shared__ __align__(16) __hip_bfloat16 As[128 * 64];
    __shared__ __align__(16) __hip_bfloat16 Bs[128 * 64];
    const int tid = threadIdx.x;
    const int lane = tid & 63, wv = tid >> 6;
    const int wr = wv >> 1, wc = wv & 1;
    const int m0 = blockIdx.x * 128, n0 = blockIdx.y * 128;
    const int g = lane >> 4, c = lane & 15;

    f32x4 acc[4][4];
    #pragma unroll
    for (int i = 0; i < 4; ++i)
        #pragma unroll
        for (int j = 0; j < 4; ++j) acc[i][j] = f32x4{0.f, 0.f, 0.f, 0.f};

    for (int k0 = 0; k0 < K; k0 += 64) {
        __syncthreads();
        #pragma unroll
        for (int it = 0; it < 4; ++it) {
            int o = (it * 256 + tid) * 16;
            int row = o >> 7;                       // 64 bf16 = 128B rows
            int colb = (o ^ ((row & 7) << 4)) & 127;  // pre-swizzled source
            GLD16((const char*)(A + (size_t)(m0 + row) * K + k0) + colb, (char*)As + o);
            GLD16((const char*)(W + (size_t)(n0 + row) * K + k0) + colb, (char*)Bs + o);
        }
        __syncthreads();
        #pragma unroll
        for (int ks = 0; ks < 2; ++ks) {
            bf16x8 af[4], bfm[4];
            #pragma unroll
            for (int i = 0; i < 4; ++i) {
                int arow = wr * 64 + i * 16 + c;
                int ab = arow * 128 + ((ks * 64 + g * 16) ^ ((arow & 7) << 4));
                af[i] = *(const bf16x8*)((const char*)As + ab);
                int brow = wc * 64 + i * 16 + c;
                int bb = brow * 128 + ((ks * 64 + g * 16) ^ ((brow & 7) << 4));
                bfm[i] = *(const bf16x8*)((const char*)Bs + bb);
            }
            #pragma unroll
            for (int i = 0; i < 4; ++i)
                #pragma unroll
                for (int j = 0; j < 4; ++j)
                    acc[i][j] = MFMA16(af[i], bfm[j], acc[i][j]);
        }
    }

    // epilogue: C frag layout col = lane&15, row = 4*(lane>>4)+r
    #pragma unroll
    for (int i = 0; i < 4; ++i) {
        #pragma unroll
        for (int j = 0; j < 4; ++j) {
            #pragma unroll
            for (int r = 0; r < 4; ++r) {
                int m = m0 + wr * 64 + i * 16 + 4 * g + r;
                int n = n0 + wc * 64 + j * 16 + c;
                float v = acc[i][j][r];
                if (OUTMODE == 2) {
                    ((float*)Cout)[(size_t)m * N + n] = v;
                } else if (OUTMODE == 0) {
                    // m=(b,s) n=(h,d) -> ((b*16+h)*2048+s)*128+d
                    size_t a = ((size_t)((m >> 11) * 16 + (n >> 7)) * S_ + (m & (S_ - 1))) * DK_ + (n & (DK_ - 1));
                    ((__hip_bfloat16*)Cout)[a] = __float2bfloat16(v);
                } else {
                    // m=(h,d) n=(b,s) -> ((b*16+h)*128+d)*2048+s
                    size_t a = ((size_t)((n >> 11) * 16 + (m >> 7)) * DK_ + (m & (DK_ - 1))) * S_ + (n & (S_ - 1));
                    ((__hip_bfloat16*)Cout)[a] = __float2bfloat16(v);
                }
            }
        }
    }
}

// ---------------- flash attention (causal), balanced pairs + double-buffered K/V ---------
// grid (16, B*H): block p handles q-tiles {p, 31-p} -> exactly 33 KV-tile units/block.
// 4 waves x 16 q-rows = 64-row q-tile, KVBLK=64. 2-phase pipeline: STAGE(next) issued
// before compute(cur); __syncthreads drains vmcnt at tile end (T3 minimum recipe).
__device__ __forceinline__ void stage_kv(const __hip_bfloat16* Kp, const __hip_bfloat16* Vp,
                                         char* ks, char* vs, int kv0, int tid) {
    #pragma unroll
    for (int it = 0; it < 4; ++it) {  // K tile: [64][128] bf16, 256B rows
        int o = (it * 256 + tid) * 16;
        int row = o >> 8;
        int cb = (o ^ ((row & 7) << 4)) & 255;
        GLD16((const char*)(Kp + (size_t)(kv0 + row) * DK_) + cb, ks + o);
    }
    #pragma unroll
    for (int it = 0; it < 4; ++it) {  // V^T tile: [128][64] bf16, 128B rows
        int o = (it * 256 + tid) * 16;
        int row = o >> 7;
        int cb = (o ^ ((row & 7) << 4)) & 127;
        GLD16((const char*)(Vp + (size_t)row * S_ + kv0) + cb, vs + o);
    }
}

__global__ __launch_bounds__(256, 2)
void attn_kernel(const __hip_bfloat16* __restrict__ Q,   // (B,H,S,DK) roped
                 const __hip_bfloat16* __restrict__ Kt,  // (B,H,S,DK) roped
                 const __hip_bfloat16* __restrict__ VT,  // (B,H,DK,S)
                 __hip_bfloat16* __restrict__ O)         // (B,S,H*DK)
{
    __shared__ __align__(16) __hip_bfloat16 Ks[2][64 * 128];   // [key][d], swizzled
    __shared__ __align__(16) __hip_bfloat16 Vs[2][128 * 64];   // [d][key], swizzled
    __shared__ __align__(16) __hip_bfloat16 Ps[4][16 * 72];    // per-wave P, padded rows

    const int tid = threadIdx.x, lane = tid & 63, w = tid >> 6;
    const int g = lane >> 4, c = lane & 15;
    const int bh = blockIdx.y, b = bh >> 4, h = bh & 15;
    const size_t base_bh = (size_t)bh * S_ * DK_;
    const __hip_bfloat16* Qp = Q + base_bh;
    const __hip_bfloat16* Kp = Kt + base_bh;
    const __hip_bfloat16* Vp = VT + base_bh;

    #pragma unroll 1
    for (int pass = 0; pass < 2; ++pass) {
        const int qt = pass ? (31 - (int)blockIdx.x) : (int)blockIdx.x;
        const int qw = qt * 64 + w * 16;
        const int ntiles = qt + 1;

        // Q fragments: lane holds Q[qw+c][ds*32 + g*8 + j]
        bf16x8 qf[4];
        #pragma unroll
        for (int ds = 0; ds < 4; ++ds)
            qf[ds] = *(const bf16x8*)(Qp + (size_t)(qw + c) * DK_ + ds * 32 + g * 8);

        f32x4 oacc[8];
        #pragma unroll
        for (int fd = 0; fd < 8; ++fd) oacc[fd] = f32x4{0.f, 0.f, 0.f, 0.f};
        float M[4], L[4];
        #pragma unroll
        for (int r = 0; r < 4; ++r) { M[r] = -1e30f; L[r] = 0.f; }

        stage_kv(Kp, Vp, (char*)Ks[0], (char*)Vs[0], 0, tid);
        __syncthreads();   // compiler drains vmcnt(0) before barrier

        int cur = 0;
        for (int t = 0; t < ntiles; ++t) {
            const int kv0 = t * 64;
            if (t + 1 < ntiles)
                stage_kv(Kp, Vp, (char*)Ks[cur ^ 1], (char*)Vs[cur ^ 1], kv0 + 64, tid);

            const bool diag = (kv0 + 63 > qw);  // wave-uniform

            // QK^T: sacc[f]: row=q_local=4g+r, col=key=f*16+c (raw scores, scale folded later)
            f32x4 sacc[4];
            #pragma unroll
            for (int f = 0; f < 4; ++f) sacc[f] = f32x4{0.f, 0.f, 0.f, 0.f};
            #pragma unroll
            for (int f = 0; f < 4; ++f) {
                #pragma unroll
                for (int ds = 0; ds < 4; ++ds) {
                    int krow = f * 16 + c;
                    int kbyt = krow * 256 + ((ds * 64 + g * 16) ^ ((krow & 7) << 4));
                    bf16x8 kf = *(const bf16x8*)((const char*)Ks[cur] + kbyt);
                    sacc[f] = MFMA16(qf[ds], kf, sacc[f]);
                }
            }

            float p[4][4];
            float mt[4] = {-1e30f, -1e30f, -1e30f, -1e30f};
            #pragma unroll
            for (int f = 0; f < 4; ++f)
                #pragma unroll
                for (int r = 0; r < 4; ++r) {
                    float v = sacc[f][r];
                    if (diag && (kv0 + f * 16 + c > qw + 4 * g + r)) v = -1e30f;
                    p[f][r] = v;
                    mt[r] = fmaxf(mt[r], v);
                }
            #pragma unroll
            for (int r = 0; r < 4; ++r) {  // row-max across the 16-lane group
                float v = mt[r];
                v = fmaxf(v, __shfl_xor(v, 1));
                v = fmaxf(v, __shfl_xor(v, 2));
                v = fmaxf(v, __shfl_xor(v, 4));
                v = fmaxf(v, __shfl_xor(v, 8));
                mt[r] = v;
            }
            // defer-max (T13): only rescale when max grew by > 8 post-scale units
            bool grow = (mt[0] > M[0] + THR_RAW_) || (mt[1] > M[1] + THR_RAW_) ||
                        (mt[2] > M[2] + THR_RAW_) || (mt[3] > M[3] + THR_RAW_);
            if (__any(grow)) {
                float al[4];
                #pragma unroll
                for (int r = 0; r < 4; ++r) {
                    float mn = fmaxf(M[r], mt[r]);
                    al[r] = __expf((M[r] - mn) * SCALE_);
                    M[r] = mn;
                    L[r] *= al[r];
                }
                #pragma unroll
                for (int fd = 0; fd < 8; ++fd)
                    #pragma unroll
                    for (int r = 0; r < 4; ++r) oacc[fd][r] *= al[r];
            }
            float ms[4];
            #pragma unroll
            for (int r = 0; r < 4; ++r) ms[r] = M[r] * SCALE_;
            float lt[4] = {0.f, 0.f, 0.f, 0.f};
            #pragma unroll
            for (int f = 0; f < 4; ++f)
                #pragma unroll
                for (int r = 0; r < 4; ++r) {
                    float e = __expf(__builtin_fmaf(p[f][r], SCALE_, -ms[r]));
                    lt[r] += e;
                    Ps[w][(4 * g + r) * 72 + f * 16 + c] = __float2bfloat16(e);
                }
            #pragma unroll
            for (int r = 0; r < 4; ++r) {
                float v = lt[r];
                v += __shfl_xor(v, 1);
                v += __shfl_xor(v, 2);
                v += __shfl_xor(v, 4);
                v += __shfl_xor(v, 8);
                L[r] += v;
            }

            // PV: A = P (row=q=lane&15, k=key), B = V^T rows (col=d)
            #pragma unroll
            for (int ks2 = 0; ks2 < 2; ++ks2) {
                bf16x8 pf = *(const bf16x8*)&Ps[w][c * 72 + ks2 * 32 + g * 8];
                #pragma unroll
                for (int fd = 0; fd < 8; ++fd) {
                    int vrow = fd * 16 + c;
                    int vb = vrow * 128 + ((ks2 * 64 + g * 16) ^ ((vrow & 7) << 4));
                    bf16x8 vf = *(const bf16x8*)((const char*)Vs[cur] + vb);
                    oacc[fd] = MFMA16(pf, vf, oacc[fd]);
                }
            }
            __syncthreads();   // drains vmcnt(0) for the prefetch; releases buf for overwrite
            cur ^= 1;
        }

        // epilogue: O[b][s][h*128+d], d = fd*16+c, s = qw+4g+r
        float rl[4];
        #pragma unroll
        for (int r = 0; r < 4; ++r) rl[r] = 1.0f / L[r];
        #pragma unroll
        for (int fd = 0; fd < 8; ++fd) {
            #pragma unroll
            for (int r = 0; r < 4; ++r) {
                int s = qw + 4 * g + r;
                size_t a = ((size_t)(b * S_ + s)) * (H_ * DK_) + h * DK_ + fd * 16 + c;
                O[a] = __float2bfloat16(oacc[fd][r] * rl[r]);
            }
        }
    }
}

extern "C" void kernel_launch(void* const* d_in, const int* in_sizes, int n_in,
                              void* d_out, int out_size, void* d_ws, size_t ws_size,
                              hipStream_t stream) {
    const float* x  = (const float*)d_in[0];
    const float* wq = (const float*)d_in[1];
    const float* wk = (const float*)d_in[2];
    const float* wv = (const float*)d_in[3];
    const float* wo = (const float*)d_in[4];
    const float* pe = (const float*)d_in[5];
    float* out = (float*)d_out;

    const size_t XE = (size_t)B_ * S_ * E_;   // 8388608
    const size_t WE = (size_t)E_ * H_ * DK_;  // 4194304
    __hip_bfloat16* xb  = (__hip_bfloat16*)d_ws;
    __hip_bfloat16* wqb = xb + XE;
    __hip_bfloat16* wkb = wqb + WE;
    __hip_bfloat16* wvb = wkb + WE;
    __hip_bfloat16* wob = wvb + WE;
    __hip_bfloat16* qb  = wob + WE;  // (B,H,S,DK)
    __hip_bfloat16* kb  = qb + XE;   // (B,H,S,DK)
    __hip_bfloat16* vT  = kb + XE;   // (B,H,DK,S)
    __hip_bfloat16* at  = vT + XE;   // (B*S, H*DK)

    cast_f32_bf16<<<dim3((int)(XE / 4 / 256)), 256, 0, stream>>>(x,  xb,  (int)(XE / 4));
    cast_f32_bf16<<<dim3((int)(WE / 4 / 256)), 256, 0, stream>>>(wq, wqb, (int)(WE / 4));
    cast_f32_bf16<<<dim3((int)(WE / 4 / 256)), 256, 0, stream>>>(wk, wkb, (int)(WE / 4));
    cast_f32_bf16<<<dim3((int)(WE / 4 / 256)), 256, 0, stream>>>(wv, wvb, (int)(WE / 4));
    cast_f32_bf16<<<dim3((int)(WE / 4 / 256)), 256, 0, stream>>>(wo, wob, (int)(WE / 4));

    // Q = x @ wq^T -> (b,h,s,d);  K likewise;  V^T = wv @ x^T -> (b,h,d,s)
    gemm_bt<0><<<dim3(32, 16), 256, 0, stream>>>(xb, wqb, qb, B_ * S_, H_ * DK_, E_);
    gemm_bt<0><<<dim3(32, 16), 256, 0, stream>>>(xb, wkb, kb, B_ * S_, H_ * DK_, E_);
    gemm_bt<1><<<dim3(16, 32), 256, 0, stream>>>(wvb, xb, vT, H_ * DK_, B_ * S_, E_);

    rope_kernel<<<dim3((int)(XE / 8 / 256), 2), 256, 0, stream>>>(qb, kb, pe);

    attn_kernel<<<dim3(16, B_ * H_), 256, 0, stream>>>(qb, kb, vT, at);

    gemm_bt<2><<<dim3(32, 16), 256, 0, stream>>>(at, wob, out, B_ * S_, E_, H_ * DK_);
}

// Round 3
// 273.435 us; speedup vs baseline: 1.3450x; 1.0958x over previous
//
#include <hip/hip_runtime.h>
#include <hip/hip_bf16.h>

typedef __attribute__((ext_vector_type(8))) short bf16x8;
typedef __attribute__((ext_vector_type(4))) float f32x4;
typedef unsigned short u16;
typedef unsigned int u32;

#define B_ 2
#define S_ 2048
#define E_ 2048
#define H_ 16
#define DK_ 128
#define SCALE_ 0.08838834764831845f  // 1/sqrt(128)
#define THR_RAW_ 90.5f               // defer-max threshold: 8 / SCALE_

#define MFMA16(a,b,c) __builtin_amdgcn_mfma_f32_16x16x32_bf16((a),(b),(c),0,0,0)
#define GLD16(g, l) __builtin_amdgcn_global_load_lds((const __attribute__((address_space(1))) void*)(g), (__attribute__((address_space(3))) void*)(l), 16, 0, 0)

__device__ __forceinline__ float b2f(short s) {
    u32 u = ((u32)(u16)s) << 16;
    float f; __builtin_memcpy(&f, &u, 4); return f;
}

// ---------------- cast f32 -> bf16 (vectorized x4) ----------------
__global__ void cast_f32_bf16(const float* __restrict__ in, __hip_bfloat16* __restrict__ out, int n4) {
    int i = blockIdx.x * blockDim.x + threadIdx.x;
    if (i >= n4) return;
    float4 v = ((const float4*)in)[i];
    __hip_bfloat16 ob[4] = {__float2bfloat16(v.x), __float2bfloat16(v.y),
                            __float2bfloat16(v.z), __float2bfloat16(v.w)};
    ushort4 u; __builtin_memcpy(&u, ob, 8);
    ((ushort4*)out)[i] = u;
}

// 4 weights in one launch (blockIdx.y selects tensor)
__global__ void cast_w4(const float* __restrict__ w0, const float* __restrict__ w1,
                        const float* __restrict__ w2, const float* __restrict__ w3,
                        __hip_bfloat16* __restrict__ o0, __hip_bfloat16* __restrict__ o1,
                        __hip_bfloat16* __restrict__ o2, __hip_bfloat16* __restrict__ o3,
                        int n4) {
    int i = blockIdx.x * blockDim.x + threadIdx.x;
    if (i >= n4) return;
    const float* in = blockIdx.y == 0 ? w0 : blockIdx.y == 1 ? w1 : blockIdx.y == 2 ? w2 : w3;
    __hip_bfloat16* out = blockIdx.y == 0 ? o0 : blockIdx.y == 1 ? o1 : blockIdx.y == 2 ? o2 : o3;
    float4 v = ((const float4*)in)[i];
    __hip_bfloat16 ob[4] = {__float2bfloat16(v.x), __float2bfloat16(v.y),
                            __float2bfloat16(v.z), __float2bfloat16(v.w)};
    ushort4 u; __builtin_memcpy(&u, ob, 8);
    ((ushort4*)out)[i] = u;
}

// ---------------- trig table: ct/st[s][d2] = cos/sin(pe[s][2*d2]) ----------------
__global__ void trig_table(const float* __restrict__ pe, float* __restrict__ ct,
                           float* __restrict__ st) {
    int t = blockIdx.x * blockDim.x + threadIdx.x;   // 0 .. S*64-1
    int s = t >> 6, d2 = t & 63;
    float ang = pe[(size_t)s * DK_ + 2 * d2];
    ct[t] = cosf(ang);
    st[t] = sinf(ang);
}

// ---------------- fused QKV projection GEMM + RoPE epilogue ----------------
// C[m][n] = sum_k x[m][k] * W[n][k]; 128x128 tile, BK=64, 4 waves (2x2).
// grid (32, 48): which = blockIdx.y/16 selects {wq,wk,wv}; ny = blockIdx.y%16.
// which<2: RoPE applied (f32), written to (b,h,s,d). which==2: written transposed (b,h,d,s).
__global__ __launch_bounds__(256, 2)
void gemm_qkv(const __hip_bfloat16* __restrict__ X,
              const __hip_bfloat16* __restrict__ WQ, const __hip_bfloat16* __restrict__ WK,
              const __hip_bfloat16* __restrict__ WV,
              __hip_bfloat16* __restrict__ Qo, __hip_bfloat16* __restrict__ Ko,
              __hip_bfloat16* __restrict__ Vo,
              const float* __restrict__ CT, const float* __restrict__ ST)
{
    __shared__ __align__(16) __hip_bfloat16 As[128 * 64];
    __shared__ __align__(16) __hip_bfloat16 Bs[128 * 64];
    const int tid = threadIdx.x;
    const int lane = tid & 63, wv = tid >> 6;
    const int wr = wv >> 1, wc = wv & 1;
    const int which = blockIdx.y >> 4;
    const __hip_bfloat16* W = which == 0 ? WQ : which == 1 ? WK : WV;
    const int m0 = blockIdx.x * 128, n0 = (blockIdx.y & 15) * 128;
    const int g = lane >> 4, c = lane & 15;
    const int K = E_;

    f32x4 acc[4][4];
    #pragma unroll
    for (int i = 0; i < 4; ++i)
        #pragma unroll
        for (int j = 0; j < 4; ++j) acc[i][j] = f32x4{0.f, 0.f, 0.f, 0.f};

    for (int k0 = 0; k0 < K; k0 += 64) {
        __syncthreads();
        #pragma unroll
        for (int it = 0; it < 4; ++it) {
            int o = (it * 256 + tid) * 16;
            int row = o >> 7;
            int colb = (o ^ ((row & 7) << 4)) & 127;
            GLD16((const char*)(X + (size_t)(m0 + row) * K + k0) + colb, (char*)As + o);
            GLD16((const char*)(W + (size_t)(n0 + row) * K + k0) + colb, (char*)Bs + o);
        }
        __syncthreads();
        #pragma unroll
        for (int ks = 0; ks < 2; ++ks) {
            bf16x8 af[4], bfm[4];
            #pragma unroll
            for (int i = 0; i < 4; ++i) {
                int arow = wr * 64 + i * 16 + c;
                int ab = arow * 128 + ((ks * 64 + g * 16) ^ ((arow & 7) << 4));
                af[i] = *(const bf16x8*)((const char*)As + ab);
                int brow = wc * 64 + i * 16 + c;
                int bb = brow * 128 + ((ks * 64 + g * 16) ^ ((brow & 7) << 4));
                bfm[i] = *(const bf16x8*)((const char*)Bs + bb);
            }
            #pragma unroll
            for (int i = 0; i < 4; ++i)
                #pragma unroll
                for (int j = 0; j < 4; ++j)
                    acc[i][j] = MFMA16(af[i], bfm[j], acc[i][j]);
        }
    }

    if (which < 2) {
        __hip_bfloat16* Cq = which == 0 ? Qo : Ko;
        #pragma unroll
        for (int i = 0; i < 4; ++i)
            #pragma unroll
            for (int j = 0; j < 4; ++j)
                #pragma unroll
                for (int r = 0; r < 4; ++r) {
                    float v = acc[i][j][r];
                    float vp = __shfl_xor(v, 1);   // partner d^1 (c parity == d parity)
                    int m = m0 + wr * 64 + i * 16 + 4 * g + r;
                    int n = n0 + wc * 64 + j * 16 + c;
                    int srow = m & (S_ - 1), d = n & (DK_ - 1);
                    float cs = CT[srow * 64 + (d >> 1)];
                    float sn = ST[srow * 64 + (d >> 1)];
                    float o = (c & 1) ? __builtin_fmaf(v, cs, vp * sn)
                                      : __builtin_fmaf(v, cs, -vp * sn);
                    size_t a = ((size_t)((m >> 11) * 16 + (n >> 7)) * S_ + srow) * DK_ + d;
                    Cq[a] = __float2bfloat16(o);
                }
    } else {
        // V: write transposed (b,h,d,s); 4 consecutive s per lane -> packed 8B store
        #pragma unroll
        for (int i = 0; i < 4; ++i)
            #pragma unroll
            for (int j = 0; j < 4; ++j) {
                int m = m0 + wr * 64 + i * 16 + 4 * g;     // r=0 row
                int n = n0 + wc * 64 + j * 16 + c;
                int s0 = m & (S_ - 1), d = n & (DK_ - 1);
                __hip_bfloat16 ob[4];
                #pragma unroll
                for (int r = 0; r < 4; ++r) ob[r] = __float2bfloat16(acc[i][j][r]);
                ushort4 u; __builtin_memcpy(&u, ob, 8);
                size_t a = ((size_t)((m >> 11) * 16 + (n >> 7)) * DK_ + d) * S_ + s0;
                *(ushort4*)(Vo + a) = u;
            }
    }
}

// ---------------- out-projection GEMM (f32 out) ----------------
__global__ __launch_bounds__(256, 2)
void gemm_out(const __hip_bfloat16* __restrict__ A, const __hip_bfloat16* __restrict__ W,
              float* __restrict__ Cout, int M, int N, int K)
{
    __shared__ __align__(16) __hip_bfloat16 As[128 * 64];
    __shared__ __align__(16) __hip_bfloat16 Bs[128 * 64];
    const int tid = threadIdx.x;
    const int lane = tid & 63, wv = tid >> 6;
    const int wr = wv >> 1, wc = wv & 1;
    const int m0 = blockIdx.x * 128, n0 = blockIdx.y * 128;
    const int g = lane >> 4, c = lane & 15;

    f32x4 acc[4][4];
    #pragma unroll
    for (int i = 0; i < 4; ++i)
        #pragma unroll
        for (int j = 0; j < 4; ++j) acc[i][j] = f32x4{0.f, 0.f, 0.f, 0.f};

    for (int k0 = 0; k0 < K; k0 += 64) {
        __syncthreads();
        #pragma unroll
        for (int it = 0; it < 4; ++it) {
            int o = (it * 256 + tid) * 16;
            int row = o >> 7;
            int colb = (o ^ ((row & 7) << 4)) & 127;
            GLD16((const char*)(A + (size_t)(m0 + row) * K + k0) + colb, (char*)As + o);
            GLD16((const char*)(W + (size_t)(n0 + row) * K + k0) + colb, (char*)Bs + o);
        }
        __syncthreads();
        #pragma unroll
        for (int ks = 0; ks < 2; ++ks) {
            bf16x8 af[4], bfm[4];
            #pragma unroll
            for (int i = 0; i < 4; ++i) {
                int arow = wr * 64 + i * 16 + c;
                int ab = arow * 128 + ((ks * 64 + g * 16) ^ ((arow & 7) << 4));
                af[i] = *(const bf16x8*)((const char*)As + ab);
                int brow = wc * 64 + i * 16 + c;
                int bb = brow * 128 + ((ks * 64 + g * 16) ^ ((brow & 7) << 4));
                bfm[i] = *(const bf16x8*)((const char*)Bs + bb);
            }
            #pragma unroll
            for (int i = 0; i < 4; ++i)
                #pragma unroll
                for (int j = 0; j < 4; ++j)
                    acc[i][j] = MFMA16(af[i], bfm[j], acc[i][j]);
        }
    }

    #pragma unroll
    for (int i = 0; i < 4; ++i)
        #pragma unroll
        for (int j = 0; j < 4; ++j)
            #pragma unroll
            for (int r = 0; r < 4; ++r) {
                int m = m0 + wr * 64 + i * 16 + 4 * g + r;
                int n = n0 + wc * 64 + j * 16 + c;
                Cout[(size_t)m * N + n] = acc[i][j][r];
            }
}

// ---------------- flash attention (causal), XCD-swizzled + balanced pairs ---------
// 512 blocks: slot = id&7 (XCD), bh = (id>>7)<<3 | slot  -> one head's K/V on ONE XCD L2.
// Block handles q-tiles {xq, 31-xq} (xq = (id>>3)&15) -> exactly 33 KV-tile units.
__device__ __forceinline__ void stage_kv(const __hip_bfloat16* Kp, const __hip_bfloat16* Vp,
                                         char* ks, char* vs, int kv0, int tid) {
    #pragma unroll
    for (int it = 0; it < 4; ++it) {  // K tile: [64][128] bf16, 256B rows
        int o = (it * 256 + tid) * 16;
        int row = o >> 8;
        int cb = (o ^ ((row & 7) << 4)) & 255;
        GLD16((const char*)(Kp + (size_t)(kv0 + row) * DK_) + cb, ks + o);
    }
    #pragma unroll
    for (int it = 0; it < 4; ++it) {  // V^T tile: [128][64] bf16, 128B rows
        int o = (it * 256 + tid) * 16;
        int row = o >> 7;
        int cb = (o ^ ((row & 7) << 4)) & 127;
        GLD16((const char*)(Vp + (size_t)row * S_ + kv0) + cb, vs + o);
    }
}

__global__ __launch_bounds__(256, 2)
void attn_kernel(const __hip_bfloat16* __restrict__ Q,   // (B,H,S,DK) roped
                 const __hip_bfloat16* __restrict__ Kt,  // (B,H,S,DK) roped
                 const __hip_bfloat16* __restrict__ VT,  // (B,H,DK,S)
                 __hip_bfloat16* __restrict__ O)         // (B,S,H*DK)
{
    __shared__ __align__(16) __hip_bfloat16 Ks[2][64 * 128];   // [key][d], swizzled
    __shared__ __align__(16) __hip_bfloat16 Vs[2][128 * 64];   // [d][key], swizzled
    __shared__ __align__(16) __hip_bfloat16 Ps[4][16 * 72];    // per-wave P, padded rows

    const int tid = threadIdx.x, lane = tid & 63, w = tid >> 6;
    const int g = lane >> 4, c = lane & 15;
    // XCD-aware remap: id%8 == bh%8 so a head's 16 blocks share one XCD's L2
    const int id = blockIdx.x;
    const int slot = id & 7, jj = id >> 3;
    const int bh = ((jj >> 4) << 3) | slot;          // 0..31
    const int xq = jj & 15;                          // 0..15
    const int b = bh >> 4, h = bh & 15;
    const size_t base_bh = (size_t)bh * S_ * DK_;
    const __hip_bfloat16* Qp = Q + base_bh;
    const __hip_bfloat16* Kp = Kt + base_bh;
    const __hip_bfloat16* Vp = VT + base_bh;

    #pragma unroll 1
    for (int pass = 0; pass < 2; ++pass) {
        const int qt = pass ? (31 - xq) : xq;
        const int qw = qt * 64 + w * 16;
        const int ntiles = qt + 1;

        // Q fragments: lane holds Q[qw+c][ds*32 + g*8 + j]
        bf16x8 qf[4];
        #pragma unroll
        for (int ds = 0; ds < 4; ++ds)
            qf[ds] = *(const bf16x8*)(Qp + (size_t)(qw + c) * DK_ + ds * 32 + g * 8);

        f32x4 oacc[8];
        #pragma unroll
        for (int fd = 0; fd < 8; ++fd) oacc[fd] = f32x4{0.f, 0.f, 0.f, 0.f};
        float M[4], L[4];
        #pragma unroll
        for (int r = 0; r < 4; ++r) { M[r] = -1e30f; L[r] = 0.f; }

        stage_kv(Kp, Vp, (char*)Ks[0], (char*)Vs[0], 0, tid);
        __syncthreads();   // compiler drains vmcnt(0) before barrier

        int cur = 0;
        for (int t = 0; t < ntiles; ++t) {
            const int kv0 = t * 64;
            if (t + 1 < ntiles)
                stage_kv(Kp, Vp, (char*)Ks[cur ^ 1], (char*)Vs[cur ^ 1], kv0 + 64, tid);

            const bool diag = (kv0 + 63 > qw);  // wave-uniform

            // QK^T: sacc[f]: row=q_local=4g+r, col=key=f*16+c (raw scores)
            f32x4 sacc[4];
            #pragma unroll
            for (int f = 0; f < 4; ++f) sacc[f] = f32x4{0.f, 0.f, 0.f, 0.f};
            #pragma unroll
            for (int f = 0; f < 4; ++f) {
                #pragma unroll
                for (int ds = 0; ds < 4; ++ds) {
                    int krow = f * 16 + c;
                    int kbyt = krow * 256 + ((ds * 64 + g * 16) ^ ((krow & 7) << 4));
                    bf16x8 kf = *(const bf16x8*)((const char*)Ks[cur] + kbyt);
                    sacc[f] = MFMA16(qf[ds], kf, sacc[f]);
                }
            }

            float p[4][4];
            float mt[4] = {-1e30f, -1e30f, -1e30f, -1e30f};
            #pragma unroll
            for (int f = 0; f < 4; ++f)
                #pragma unroll
                for (int r = 0; r < 4; ++r) {
                    float v = sacc[f][r];
                    if (diag && (kv0 + f * 16 + c > qw + 4 * g + r)) v = -1e30f;
                    p[f][r] = v;
                    mt[r] = fmaxf(mt[r], v);
                }
            #pragma unroll
            for (int r = 0; r < 4; ++r) {  // row-max across the 16-lane group
                float v = mt[r];
                v = fmaxf(v, __shfl_xor(v, 1));
                v = fmaxf(v, __shfl_xor(v, 2));
                v = fmaxf(v, __shfl_xor(v, 4));
                v = fmaxf(v, __shfl_xor(v, 8));
                mt[r] = v;
            }
            // defer-max (T13)
            bool grow = (mt[0] > M[0] + THR_RAW_) || (mt[1] > M[1] + THR_RAW_) ||
                        (mt[2] > M[2] + THR_RAW_) || (mt[3] > M[3] + THR_RAW_);
            if (__any(grow)) {
                float al[4];
                #pragma unroll
                for (int r = 0; r < 4; ++r) {
                    float mn = fmaxf(M[r], mt[r]);
                    al[r] = __expf((M[r] - mn) * SCALE_);
                    M[r] = mn;
                    L[r] *= al[r];
                }
                #pragma unroll
                for (int fd = 0; fd < 8; ++fd)
                    #pragma unroll
                    for (int r = 0; r < 4; ++r) oacc[fd][r] *= al[r];
            }
            float ms[4];
            #pragma unroll
            for (int r = 0; r < 4; ++r) ms[r] = M[r] * SCALE_;
            float lt[4] = {0.f, 0.f, 0.f, 0.f};
            #pragma unroll
            for (int f = 0; f < 4; ++f)
                #pragma unroll
                for (int r = 0; r < 4; ++r) {
                    float e = __expf(__builtin_fmaf(p[f][r], SCALE_, -ms[r]));
                    lt[r] += e;
                    Ps[w][(4 * g + r) * 72 + f * 16 + c] = __float2bfloat16(e);
                }
            #pragma unroll
            for (int r = 0; r < 4; ++r) {
                float v = lt[r];
                v += __shfl_xor(v, 1);
                v += __shfl_xor(v, 2);
                v += __shfl_xor(v, 4);
                v += __shfl_xor(v, 8);
                L[r] += v;
            }

            // PV: A = P (row=q=lane&15, k=key), B = V^T rows (col=d)
            #pragma unroll
            for (int ks2 = 0; ks2 < 2; ++ks2) {
                bf16x8 pf = *(const bf16x8*)&Ps[w][c * 72 + ks2 * 32 + g * 8];
                #pragma unroll
                for (int fd = 0; fd < 8; ++fd) {
                    int vrow = fd * 16 + c;
                    int vb = vrow * 128 + ((ks2 * 64 + g * 16) ^ ((vrow & 7) << 4));
                    bf16x8 vf = *(const bf16x8*)((const char*)Vs[cur] + vb);
                    oacc[fd] = MFMA16(pf, vf, oacc[fd]);
                }
            }
            __syncthreads();   // drains vmcnt(0) for prefetch; releases buf
            cur ^= 1;
        }

        // epilogue: O[b][s][h*128+d]
        float rl[4];
        #pragma unroll
        for (int r = 0; r < 4; ++r) rl[r] = 1.0f / L[r];
        #pragma unroll
        for (int fd = 0; fd < 8; ++fd) {
            #pragma unroll
            for (int r = 0; r < 4; ++r) {
                int s = qw + 4 * g + r;
                size_t a = ((size_t)(b * S_ + s)) * (H_ * DK_) + h * DK_ + fd * 16 + c;
                O[a] = __float2bfloat16(oacc[fd][r] * rl[r]);
            }
        }
    }
}

extern "C" void kernel_launch(void* const* d_in, const int* in_sizes, int n_in,
                              void* d_out, int out_size, void* d_ws, size_t ws_size,
                              hipStream_t stream) {
    const float* x  = (const float*)d_in[0];
    const float* wq = (const float*)d_in[1];
    const float* wk = (const float*)d_in[2];
    const float* wv = (const float*)d_in[3];
    const float* wo = (const float*)d_in[4];
    const float* pe = (const float*)d_in[5];
    float* out = (float*)d_out;

    const size_t XE = (size_t)B_ * S_ * E_;   // 8388608
    const size_t WE = (size_t)E_ * H_ * DK_;  // 4194304
    __hip_bfloat16* xb  = (__hip_bfloat16*)d_ws;
    __hip_bfloat16* wqb = xb + XE;
    __hip_bfloat16* wkb = wqb + WE;
    __hip_bfloat16* wvb = wkb + WE;
    __hip_bfloat16* wob = wvb + WE;
    __hip_bfloat16* qb  = wob + WE;  // (B,H,S,DK)
    __hip_bfloat16* kb  = qb + XE;   // (B,H,S,DK)
    __hip_bfloat16* vT  = kb + XE;   // (B,H,DK,S)
    __hip_bfloat16* at  = vT + XE;   // (B*S, H*DK)
    float* ct = (float*)(at + XE);   // cos table S*64
    float* st = ct + (size_t)S_ * 64;

    cast_f32_bf16<<<dim3((int)(XE / 4 / 256)), 256, 0, stream>>>(x, xb, (int)(XE / 4));
    cast_w4<<<dim3((int)(WE / 4 / 256), 4), 256, 0, stream>>>(wq, wk, wv, wo,
                                                              wqb, wkb, wvb, wob,
                                                              (int)(WE / 4));
    trig_table<<<dim3(S_ * 64 / 256), 256, 0, stream>>>(pe, ct, st);

    gemm_qkv<<<dim3(32, 48), 256, 0, stream>>>(xb, wqb, wkb, wvb, qb, kb, vT, ct, st);

    attn_kernel<<<dim3(512), 256, 0, stream>>>(qb, kb, vT, at);

    gemm_out<<<dim3(32, 16), 256, 0, stream>>>(at, wob, out, B_ * S_, E_, H_ * DK_);
}